// Round 11
// baseline (305.224 us; speedup 1.0000x reference)
//
#include <hip/hip_runtime.h>

typedef _Float16 half_t;
typedef __attribute__((ext_vector_type(8))) _Float16 half8;
typedef __attribute__((ext_vector_type(4))) _Float16 half4;
typedef __attribute__((ext_vector_type(4))) float float4_t;

#define BN_EPS 1e-5f

constexpr int Nn = 64, Cc = 64, Tt = 300, Vv = 25, Ss = 3;
constexpr int XA_S = 72;    // c-stride of wave-private xa rows (144 B: 16B-aligned, ~2-way banks)
constexpr int TB   = 8;     // timesteps per block -> 800 B read/write granules per c-row
constexpr int XH_S = 264;   // halfs per xh c-row: 8*32 + 8 pad (528 B = 132 dw = 4 mod 32 banks)

// ---------------- precompute: fragment-major fp16 tables into workspace ----------------
// aeh[s][wt][lane][8] : Ae^T fragment  B[k=v][n=w], v=(lane>>4)*8+j, w=wt*16+(lane&15), zero-padded
// wch[s][ot][ks][lane][8] : Wc fragment A[m=o][k=c], o=ot*16+(lane&15), c=ks*32+(lane>>4)*8+j
__global__ __launch_bounds__(256, 1)
void gcn_pre(const float* __restrict__ A,   const float* __restrict__ PA1,
             const float* __restrict__ PA2, const float* __restrict__ Wc,
             const float* __restrict__ bc,  const float* __restrict__ gamma,
             const float* __restrict__ beta, const float* __restrict__ rmean,
             const float* __restrict__ rvar,
             half_t* __restrict__ aeh, half_t* __restrict__ wch,
             float* __restrict__ bnsc, float* __restrict__ bnsh)
{
    const int tid = threadIdx.x;
    if (tid < Cc) {
        float sc   = gamma[tid] * rsqrtf(rvar[tid] + BN_EPS);
        float bsum = bc[tid] + bc[Cc + tid] + bc[2 * Cc + tid];
        bnsc[tid] = sc;
        bnsh[tid] = beta[tid] - rmean[tid] * sc + bsum * sc;
    }
    for (int e = tid; e < Ss * 2 * 64; e += 256) {        // AeT fragments
        int s = e >> 7, wt = (e >> 6) & 1, lane = e & 63;
        int col = lane & 15, q = lane >> 4;
        int w = wt * 16 + col;
        #pragma unroll
        for (int j = 0; j < 8; ++j) {
            int v = q * 8 + j;
            float val = 0.f;
            if (v < Vv && w < Vv) {
                int ai = (s * Vv + v) * Vv + w;
                val = A[ai] * PA1[ai] + PA2[ai];
            }
            aeh[e * 8 + j] = (half_t)val;
        }
    }
    for (int e = tid; e < Ss * 4 * 2 * 64; e += 256) {    // Wc fragments
        int s = e >> 9, r = e & 511, ot = r >> 7, ks = (r >> 6) & 1, lane = r & 63;
        int col = lane & 15, q = lane >> 4;
        int o = ot * 16 + col;
        #pragma unroll
        for (int j = 0; j < 8; ++j) {
            int c = ks * 32 + q * 8 + j;
            wch[e * 8 + j] = (half_t)Wc[(s * Cc + o) * Cc + c];
        }
    }
}

// ---- fused main: TB=8, fp16 LDS slab (x in / out staged in-place), barrier-free s-loop ----
__global__ __launch_bounds__(256, 3)
void gcn_fused(const float* __restrict__ x, const half_t* __restrict__ aeh,
               const half_t* __restrict__ wch, const float* __restrict__ bnsc,
               const float* __restrict__ bnsh, float* __restrict__ out)
{
    // fp16 slab [c][t 0..7][v 0..31], v>=25 zero (K-pad). Holds x, then (in-place) out. 33792 B
    __shared__ __align__(16) half_t xh[Cc * XH_S];
    // wave-private xa transpose scratch: [wave][w 0..31][c 0..63 +pad] = 18432 B
    __shared__ __align__(16) half_t xaW[4][32][XA_S];
    // total 52224 B -> 3 blocks/CU (12 waves/CU, ~170-reg tier)

    const int tid  = threadIdx.x;
    const int lane = tid & 63;
    const int wave = tid >> 6;      // 0..3
    const int col  = lane & 15;
    const int quad = lane >> 4;

    const int n  = blockIdx.y;
    const int t0 = blockIdx.x * TB;                   // 0,8,...,296 (last block has 4 valid t)
    const int tlim = min(TB, Tt - t0);                // 8, or 4 for the tail block
    const int nq   = (tlim * Vv) / 4;                 // float4s per c-row: 50 or 25 (both exact)
    const float* xb = x + (size_t)n * Cc * Tt * Vv + t0 * Vv;

    // ---- zero the v-pads (v=25..31) for all 8 t (pads persist through in-place epilogue) ----
    for (int i = tid; i < Cc * TB * 7; i += 256) {    // 3584
        int c = i / 56, r = i - c * 56, t = r / 7, v = 25 + r - (r / 7) * 7;
        xh[c * XH_S + t * 32 + v] = (half_t)0.f;
    }

    // ---- stage x: 800 B contiguous granule per c-row (50 float4), reg round-trip -> fp16 ----
    #pragma unroll
    for (int k = 0; k < 13; ++k) {
        int f = tid + k * 256;
        if (f < Cc * 50) {
            int c = f / 50, q = f - c * 50;
            if (q < nq) {
                float4_t d = *(const float4_t*)(xb + c * (Tt * Vv) + q * 4);  // 16B-aligned
                int g = q * 4;
                #pragma unroll
                for (int j = 0; j < 4; ++j) {
                    int gg = g + j, t = gg / 25, v = gg - t * 25;
                    xh[c * XH_S + t * 32 + v] = (half_t)d[j];
                }
            }
        }
    }

    // ---- Ae^T B-fragments, all s (L1/L2-hot table) — overlaps staging latency ----
    half8 ab[Ss][2];
    #pragma unroll
    for (int s = 0; s < Ss; ++s)
        #pragma unroll
        for (int wt = 0; wt < 2; ++wt)
            ab[s][wt] = *(const half8*)&aeh[((s * 2 + wt) * 64 + lane) * 8];

    __syncthreads();   // slab complete & visible to all waves

    const float4_t zero4 = {0.f, 0.f, 0.f, 0.f};

    for (int tt = 0; tt < 2; ++tt) {
        const int tl = tt * 4 + wave;                 // local t owned by this wave this pass
        const int tg = t0 + tl;
        if (tg < Tt) {                                // wave-uniform; no barriers inside
            // ---- af fragments: direct half8 reads from slab (no cvt) ----
            half8 af[4];
            #pragma unroll
            for (int ct = 0; ct < 4; ++ct)
                af[ct] = *(const half8*)&xh[(ct * 16 + col) * XH_S + tl * 32 + quad * 8];

            float4_t yacc[4][2];
            #pragma unroll
            for (int ot = 0; ot < 4; ++ot)
                #pragma unroll
                for (int wt = 0; wt < 2; ++wt) yacc[ot][wt] = zero4;

            #pragma unroll
            for (int s = 0; s < Ss; ++s) {
                // ---- stage 1: xa[c][w] = x · Ae[s] (8 MFMA) ----
                #pragma unroll
                for (int ct = 0; ct < 4; ++ct)
                    #pragma unroll
                    for (int wt = 0; wt < 2; ++wt) {
                        float4_t r = __builtin_amdgcn_mfma_f32_16x16x32_f16(af[ct], ab[s][wt], zero4, 0, 0, 0);
                        half4 h;
                        #pragma unroll
                        for (int i = 0; i < 4; ++i) h[i] = (half_t)r[i];
                        *(half4*)&xaW[wave][wt * 16 + col][ct * 16 + quad * 4] = h;
                    }
                // ---- same-wave transpose readback (lgkmcnt-ordered, NO barrier) ----
                half8 bf[2][2];
                #pragma unroll
                for (int ks = 0; ks < 2; ++ks)
                    #pragma unroll
                    for (int wt = 0; wt < 2; ++wt)
                        bf[ks][wt] = *(const half8*)&xaW[wave][wt * 16 + col][ks * 32 + quad * 8];
                // ---- stage 2: y += Wc[s] · xa (16 MFMA), wch streamed L1-hot ----
                #pragma unroll
                for (int ot = 0; ot < 4; ++ot) {
                    half8 w0 = *(const half8*)&wch[(((s * 4 + ot) * 2 + 0) * 64 + lane) * 8];
                    half8 w1 = *(const half8*)&wch[(((s * 4 + ot) * 2 + 1) * 64 + lane) * 8];
                    #pragma unroll
                    for (int wt = 0; wt < 2; ++wt) {
                        yacc[ot][wt] = __builtin_amdgcn_mfma_f32_16x16x32_f16(w0, bf[0][wt], yacc[ot][wt], 0, 0, 0);
                        yacc[ot][wt] = __builtin_amdgcn_mfma_f32_16x16x32_f16(w1, bf[1][wt], yacc[ot][wt], 0, 0, 0);
                    }
                }
            }

            // ---- epilogue: BN + residual (slab read) -> fp16 back into the SAME slot ----
            #pragma unroll
            for (int ot = 0; ot < 4; ++ot) {
                float4_t sc = *(const float4_t*)&bnsc[ot * 16 + quad * 4];   // L1/L3-hot
                float4_t sh = *(const float4_t*)&bnsh[ot * 16 + quad * 4];
                #pragma unroll
                for (int i = 0; i < 4; ++i) {
                    const int o = ot * 16 + quad * 4 + i;
                    #pragma unroll
                    for (int wt = 0; wt < 2; ++wt) {
                        int w = wt * 16 + col;
                        if (w < Vv) {
                            const int idx = o * XH_S + tl * 32 + w;          // lane-owned slot
                            float val = yacc[ot][wt][i] * sc[i] + sh[i] + (float)xh[idx];
                            xh[idx] = (half_t)fmaxf(val, 0.f);
                        }
                    }
                }
            }
        }
    }

    __syncthreads();   // all waves' outputs staged in xh before the streamed flush

    // ---- flush: 800 B contiguous granule per c-row, fp16 -> fp32 float4 stores ----
    float* ob = out + (size_t)n * Cc * Tt * Vv + t0 * Vv;
    #pragma unroll
    for (int k = 0; k < 13; ++k) {
        int f = tid + k * 256;
        if (f < Cc * 50) {
            int c = f / 50, q = f - c * 50;
            if (q < nq) {
                int g = q * 4;
                float4_t d;
                #pragma unroll
                for (int j = 0; j < 4; ++j) {
                    int gg = g + j, t = gg / 25, v = gg - t * 25;
                    d[j] = (float)xh[c * XH_S + t * 32 + v];
                }
                *(float4_t*)(ob + c * (Tt * Vv) + q * 4) = d;
            }
        }
    }
}

extern "C" void kernel_launch(void* const* d_in, const int* in_sizes, int n_in,
                              void* d_out, int out_size, void* d_ws, size_t ws_size,
                              hipStream_t stream) {
    const float* x     = (const float*)d_in[0];
    const float* A     = (const float*)d_in[1];
    const float* PA1   = (const float*)d_in[2];
    const float* PA2   = (const float*)d_in[3];
    const float* Wc    = (const float*)d_in[4];
    const float* bc    = (const float*)d_in[5];
    const float* gamma = (const float*)d_in[6];
    const float* beta  = (const float*)d_in[7];
    const float* rmean = (const float*)d_in[8];
    const float* rvar  = (const float*)d_in[9];
    float* out = (float*)d_out;

    // workspace layout (31,232 B): aeh | wch | bnsc | bnsh
    half_t* aeh = (half_t*)d_ws;                      // 3*2*64*8  = 3072 halfs
    half_t* wch = aeh + Ss * 2 * 64 * 8;              // 3*4*2*64*8 = 12288 halfs
    float* bnsc = (float*)(wch + Ss * 4 * 2 * 64 * 8);
    float* bnsh = bnsc + Cc;

    gcn_pre<<<dim3(1), 256, 0, stream>>>(A, PA1, PA2, Wc, bc, gamma, beta, rmean, rvar,
                                         aeh, wch, bnsc, bnsh);
    gcn_fused<<<dim3((Tt + TB - 1) / TB, Nn), 256, 0, stream>>>(x, aeh, wch, bnsc, bnsh, out);
}

// Round 13
// 284.819 us; speedup vs baseline: 1.0716x; 1.0716x over previous
//
#include <hip/hip_runtime.h>

typedef _Float16 half_t;
typedef __attribute__((ext_vector_type(8))) _Float16 half8;
typedef __attribute__((ext_vector_type(4))) _Float16 half4;
typedef __attribute__((ext_vector_type(4))) float float4_t;

#define BN_EPS 1e-5f

constexpr int Nn = 64, Cc = 64, Tt = 300, Vv = 25, Ss = 3;
constexpr int XA_S = 72;   // c-stride of wave-private xa rows (144 B: 16B-aligned, ~2-way banks)

// ---------------- precompute: fragment-major fp16 tables into workspace ----------------
// aeh[s][wt][lane][8] : Ae^T fragment  B[k=v][n=w], v=(lane>>4)*8+j, w=wt*16+(lane&15), zero-padded
// wch[s][ot][ks][lane][8] : Wc fragment A[m=o][k=c], o=ot*16+(lane&15), c=ks*32+(lane>>4)*8+j
__global__ __launch_bounds__(256, 1)
void gcn_pre(const float* __restrict__ A,   const float* __restrict__ PA1,
             const float* __restrict__ PA2, const float* __restrict__ Wc,
             const float* __restrict__ bc,  const float* __restrict__ gamma,
             const float* __restrict__ beta, const float* __restrict__ rmean,
             const float* __restrict__ rvar,
             half_t* __restrict__ aeh, half_t* __restrict__ wch,
             float* __restrict__ bnsc, float* __restrict__ bnsh)
{
    const int tid = threadIdx.x;
    if (tid < Cc) {
        float sc   = gamma[tid] * rsqrtf(rvar[tid] + BN_EPS);
        float bsum = bc[tid] + bc[Cc + tid] + bc[2 * Cc + tid];
        bnsc[tid] = sc;
        bnsh[tid] = beta[tid] - rmean[tid] * sc + bsum * sc;
    }
    for (int e = tid; e < Ss * 2 * 64; e += 256) {        // AeT fragments
        int s = e >> 7, wt = (e >> 6) & 1, lane = e & 63;
        int col = lane & 15, q = lane >> 4;
        int w = wt * 16 + col;
        #pragma unroll
        for (int j = 0; j < 8; ++j) {
            int v = q * 8 + j;
            float val = 0.f;
            if (v < Vv && w < Vv) {
                int ai = (s * Vv + v) * Vv + w;
                val = A[ai] * PA1[ai] + PA2[ai];
            }
            aeh[e * 8 + j] = (half_t)val;
        }
    }
    for (int e = tid; e < Ss * 4 * 2 * 64; e += 256) {    // Wc fragments
        int s = e >> 9, r = e & 511, ot = r >> 7, ks = (r >> 6) & 1, lane = r & 63;
        int col = lane & 15, q = lane >> 4;
        int o = ot * 16 + col;
        #pragma unroll
        for (int j = 0; j < 8; ++j) {
            int c = ks * 32 + q * 8 + j;
            wch[e * 8 + j] = (half_t)Wc[(s * Cc + o) * Cc + c];
        }
    }
}

// ---- fused main: DMA-staged x in LDS, barrier-free s-loop, LDS-staged coalesced out ----
// (R10 structure: best verified — 97 us dispatch; FETCH+WRITE = wire-traffic minimum)
__global__ __launch_bounds__(256, 3)
void gcn_fused(const float* __restrict__ x, const half_t* __restrict__ aeh,
               const half_t* __restrict__ wch, const float* __restrict__ bnsc,
               const float* __restrict__ bnsh, float* __restrict__ out)
{
    // x slab for this (n, 4-timestep) block, raw fp32 [c][t*25+v] = 25600 B.
    // After the s-loop it is updated IN PLACE to the output values and flushed.
    __shared__ __align__(16) float xs[Cc * 100];
    // wave-private xa transpose scratch: [wave][w 0..31][c 0..63 +pad] = 18432 B
    __shared__ __align__(16) half_t xaW[4][32][XA_S];
    // total 44032 B -> 3 blocks/CU

    const int tid  = threadIdx.x;
    const int lane = tid & 63;
    const int wave = tid >> 6;      // 0..3 -> owns timestep t0+wave
    const int col  = lane & 15;
    const int quad = lane >> 4;

    const int n  = blockIdx.y;
    const int t0 = blockIdx.x * 4;                    // 0..296, exact (300/4 = 75)
    const float* xb = x + (size_t)n * Cc * Tt * Vv + t0 * Vv;

    // ---- stage x: 1600 float4 via global_load_lds (400 B granules per c-row, 0 reg cost;
    //      adjacent blockIdx.x co-resident -> effective DRAM granule >= 800 B) ----
    for (int i = tid; i < 1600; i += 256) {
        int c = i / 25, q = i - c * 25;               // q = float4 index within 100-float row
        const float* g = xb + c * (Tt * Vv) + q * 4;  // 16B-aligned (t0*100 B, c*30000 B)
        __builtin_amdgcn_global_load_lds(
            (const __attribute__((address_space(1))) unsigned int*)g,
            (__attribute__((address_space(3))) unsigned int*)&xs[i * 4],
            16, 0, 0);
    }

    // ---- Ae^T B-fragments, all s (L1/L2-hot table) — overlaps the DMA ----
    half8 ab[Ss][2];
    #pragma unroll
    for (int s = 0; s < Ss; ++s)
        #pragma unroll
        for (int wt = 0; wt < 2; ++wt)
            ab[s][wt] = *(const half8*)&aeh[((s * 2 + wt) * 64 + lane) * 8];

    __syncthreads();   // DMA drained (vmcnt0) + visible to all waves

    // ---- af fragments from LDS slab: af[ct] = x[c=ct*16+col][t=wave][v=quad*8+j] ----
    half8 af[4];
    #pragma unroll
    for (int ct = 0; ct < 4; ++ct) {
        const float* r = &xs[(ct * 16 + col) * 100 + wave * 25];
        half8 h;
        if (quad < 3) {
            #pragma unroll
            for (int j = 0; j < 8; ++j) h[j] = (half_t)r[quad * 8 + j];
        } else {
            h[0] = (half_t)r[24];                     // v=24; v=25..31 are K-pad zeros
            #pragma unroll
            for (int j = 1; j < 8; ++j) h[j] = (half_t)0.f;
        }
        af[ct] = h;
    }

    const float4_t zero4 = {0.f, 0.f, 0.f, 0.f};
    float4_t yacc[4][2];
    #pragma unroll
    for (int ot = 0; ot < 4; ++ot)
        #pragma unroll
        for (int wt = 0; wt < 2; ++wt) yacc[ot][wt] = zero4;

    #pragma unroll
    for (int s = 0; s < Ss; ++s) {
        // ---- stage 1: xa[c][w] = x · Ae[s] for this wave's t (8 MFMA) ----
        // D[m=c=ct*16+quad*4+i][n=w=wt*16+col]; Ae cols w>=25 are zero -> rows 25..31 = 0
        #pragma unroll
        for (int ct = 0; ct < 4; ++ct)
            #pragma unroll
            for (int wt = 0; wt < 2; ++wt) {
                float4_t r = __builtin_amdgcn_mfma_f32_16x16x32_f16(af[ct], ab[s][wt], zero4, 0, 0, 0);
                half4 h;
                #pragma unroll
                for (int i = 0; i < 4; ++i) h[i] = (half_t)r[i];
                *(half4*)&xaW[wave][wt * 16 + col][ct * 16 + quad * 4] = h;
            }
        // ---- same-wave transpose readback (lgkmcnt-ordered, NO barrier) ----
        half8 bf[2][2];
        #pragma unroll
        for (int ks = 0; ks < 2; ++ks)
            #pragma unroll
            for (int wt = 0; wt < 2; ++wt)
                bf[ks][wt] = *(const half8*)&xaW[wave][wt * 16 + col][ks * 32 + quad * 8];
        // ---- stage 2: y[o][w] += Wc[s] · xa  (16 MFMA), wch streamed from L1/L2 table ----
        #pragma unroll
        for (int ot = 0; ot < 4; ++ot) {
            half8 w0 = *(const half8*)&wch[(((s * 4 + ot) * 2 + 0) * 64 + lane) * 8];
            half8 w1 = *(const half8*)&wch[(((s * 4 + ot) * 2 + 1) * 64 + lane) * 8];
            #pragma unroll
            for (int wt = 0; wt < 2; ++wt) {
                yacc[ot][wt] = __builtin_amdgcn_mfma_f32_16x16x32_f16(w0, bf[0][wt], yacc[ot][wt], 0, 0, 0);
                yacc[ot][wt] = __builtin_amdgcn_mfma_f32_16x16x32_f16(w1, bf[1][wt], yacc[ot][wt], 0, 0, 0);
            }
        }
    }

    // ---- epilogue: BN + residual, IN-PLACE into xs (each (o,t,w) owned by one lane) ----
    #pragma unroll
    for (int ot = 0; ot < 4; ++ot) {
        float4_t sc = *(const float4_t*)&bnsc[ot * 16 + quad * 4];   // 16B-aligned, L3-hot
        float4_t sh = *(const float4_t*)&bnsh[ot * 16 + quad * 4];
        #pragma unroll
        for (int i = 0; i < 4; ++i) {
            const int o = ot * 16 + quad * 4 + i;
            #pragma unroll
            for (int wt = 0; wt < 2; ++wt) {
                int w = wt * 16 + col;
                if (w < Vv) {
                    const int idx = o * 100 + wave * 25 + w;
                    float val = yacc[ot][wt][i] * sc[i] + sh[i] + xs[idx];
                    xs[idx] = fmaxf(val, 0.f);
                }
            }
        }
    }

    __syncthreads();   // all waves' results in xs before the streamed flush

    // ---- flush: 64 rows x 400 B contiguous (16B/lane float4, fully coalesced) ----
    float* ob = out + (size_t)n * Cc * Tt * Vv + t0 * Vv;
    for (int i = tid; i < 1600; i += 256) {
        int c = i / 25, q = i - c * 25;
        *(float4_t*)(ob + c * (Tt * Vv) + q * 4) = *(const float4_t*)&xs[i * 4];
    }
}

extern "C" void kernel_launch(void* const* d_in, const int* in_sizes, int n_in,
                              void* d_out, int out_size, void* d_ws, size_t ws_size,
                              hipStream_t stream) {
    const float* x     = (const float*)d_in[0];
    const float* A     = (const float*)d_in[1];
    const float* PA1   = (const float*)d_in[2];
    const float* PA2   = (const float*)d_in[3];
    const float* Wc    = (const float*)d_in[4];
    const float* bc    = (const float*)d_in[5];
    const float* gamma = (const float*)d_in[6];
    const float* beta  = (const float*)d_in[7];
    const float* rmean = (const float*)d_in[8];
    const float* rvar  = (const float*)d_in[9];
    float* out = (float*)d_out;

    // workspace layout (31,232 B): aeh | wch | bnsc | bnsh
    half_t* aeh = (half_t*)d_ws;                      // 3*2*64*8  = 3072 halfs
    half_t* wch = aeh + Ss * 2 * 64 * 8;              // 3*4*2*64*8 = 12288 halfs
    float* bnsc = (float*)(wch + Ss * 4 * 2 * 64 * 8);
    float* bnsh = bnsc + Cc;

    gcn_pre<<<dim3(1), 256, 0, stream>>>(A, PA1, PA2, Wc, bc, gamma, beta, rmean, rvar,
                                         aeh, wch, bnsc, bnsh);
    gcn_fused<<<dim3(Tt / 4, Nn), 256, 0, stream>>>(x, aeh, wch, bnsc, bnsh, out);
}